// Round 3
// baseline (2403.154 us; speedup 1.0000x reference)
//
#include <hip/hip_runtime.h>

#define NA 8192
#define NB 8192
#define N_LAYERS 16
#define RPB 16          // rows per fused block
#define NBLK 512        // fused grid = NA/RPB
#define NTH 512         // threads per fused block; thread owns cols {8t..8t+7} u {4096+8t..+7}

typedef _Float16 half_t;
typedef _Float16 half8_t __attribute__((ext_vector_type(8)));
typedef float float4_t __attribute__((ext_vector_type(4)));

// LDS-only barrier: does NOT drain vmcnt, so global prefetch loads for the
// next batch stay in flight across the reduction episode.
__device__ __forceinline__ void barrier_lds() {
    asm volatile("s_waitcnt lgkmcnt(0)" ::: "memory");
    __builtin_amdgcn_s_barrier();
    asm volatile("" ::: "memory");
}

// ---------------------------------------------------------------------------
// Steady layers, full-E path (KC==16). Block = 16 rows, 4 batches of 4 rows.
// Per batch: dots vs register-resident v-slice -> ONE butterfly+barrier
// episode for 4 rows -> u -> column accumulation from the register tile.
// E is read from global exactly once per layer.
// ---------------------------------------------------------------------------
__global__ __launch_bounds__(NTH, 4) void sink_fe_full(
    const half_t* __restrict__ E, const float* __restrict__ v,
    const float* __restrict__ alpha, float* __restrict__ u,
    float* __restrict__ partial)
{
    const int t = threadIdx.x;
    const int rc = blockIdx.x;
    const int row0 = rc * RPB;
    __shared__ float4_t sred[2][8];          // [parity][wave] : 4 row-sums

    // v weights for owned cols (loaded once)
    const float4_t* vv = (const float4_t*)v;
    const float4_t wA0 = vv[2 * t], wA1 = vv[2 * t + 1];
    const float4_t wB0 = vv[1024 + 2 * t], wB1 = vv[1024 + 2 * t + 1];

    float acc[16];
#pragma unroll
    for (int j = 0; j < 16; ++j) acc[j] = 0.0f;

    const half8_t* Eb = (const half8_t*)E;
    const size_t rbase = (size_t)row0 * (NB / 8);

    half8_t eC[4][2], eN[4][2];
    auto loadB = [&](half8_t (&d)[4][2], int b) {
#pragma unroll
        for (int r = 0; r < 4; ++r) {
            const size_t ro = rbase + (size_t)(b * 4 + r) * (NB / 8);
            d[r][0] = Eb[ro + t];
            d[r][1] = Eb[ro + 512 + t];
        }
    };

    auto episode = [&](const half8_t (&e)[4][2], int b, int par) {
        float rs0, rs1, rs2, rs3;
        {
            float s[4];
#pragma unroll
            for (int r = 0; r < 4; ++r) {
                float x = 0.0f;
                x += (float)e[r][0][0] * wA0.x + (float)e[r][0][1] * wA0.y +
                     (float)e[r][0][2] * wA0.z + (float)e[r][0][3] * wA0.w;
                x += (float)e[r][0][4] * wA1.x + (float)e[r][0][5] * wA1.y +
                     (float)e[r][0][6] * wA1.z + (float)e[r][0][7] * wA1.w;
                x += (float)e[r][1][0] * wB0.x + (float)e[r][1][1] * wB0.y +
                     (float)e[r][1][2] * wB0.z + (float)e[r][1][3] * wB0.w;
                x += (float)e[r][1][4] * wB1.x + (float)e[r][1][5] * wB1.y +
                     (float)e[r][1][6] * wB1.z + (float)e[r][1][7] * wB1.w;
                s[r] = x;
            }
            rs0 = s[0]; rs1 = s[1]; rs2 = s[2]; rs3 = s[3];
        }
#pragma unroll
        for (int m = 1; m < 64; m <<= 1) {   // 4 independent 6-deep chains
            rs0 += __shfl_xor(rs0, m);
            rs1 += __shfl_xor(rs1, m);
            rs2 += __shfl_xor(rs2, m);
            rs3 += __shfl_xor(rs3, m);
        }
        if ((t & 63) == 0) sred[par][t >> 6] = float4_t{rs0, rs1, rs2, rs3};
        barrier_lds();
        float4_t S = sred[par][0];
#pragma unroll
        for (int w2 = 1; w2 < 8; ++w2) S += sred[par][w2];

        const int r0 = row0 + b * 4;
        const float u0 = alpha[r0] / S.x;
        const float u1 = alpha[r0 + 1] / S.y;
        const float u2 = alpha[r0 + 2] / S.z;
        const float u3 = alpha[r0 + 3] / S.w;
        if (t == 0) *(float4_t*)(u + r0) = float4_t{u0, u1, u2, u3};

#pragma unroll
        for (int j = 0; j < 8; ++j) {
            acc[j]     += u0 * (float)e[0][0][j] + u1 * (float)e[1][0][j] +
                          u2 * (float)e[2][0][j] + u3 * (float)e[3][0][j];
            acc[8 + j] += u0 * (float)e[0][1][j] + u1 * (float)e[1][1][j] +
                          u2 * (float)e[2][1][j] + u3 * (float)e[3][1][j];
        }
    };

    loadB(eC, 0);
    loadB(eN, 1);          // 2 batches in flight
    episode(eC, 0, 0);
    loadB(eC, 2);
    episode(eN, 1, 1);
    loadB(eN, 3);
    episode(eC, 2, 0);
    episode(eN, 3, 1);

    // partial[rc][owned cols]
    float* pr = partial + (size_t)rc * NB;
    *(float4_t*)(pr + 8 * t)        = float4_t{acc[0], acc[1], acc[2], acc[3]};
    *(float4_t*)(pr + 8 * t + 4)    = float4_t{acc[4], acc[5], acc[6], acc[7]};
    *(float4_t*)(pr + 4096 + 8 * t)     = float4_t{acc[8], acc[9], acc[10], acc[11]};
    *(float4_t*)(pr + 4096 + 8 * t + 4) = float4_t{acc[12], acc[13], acc[14], acc[15]};
}

// ---------------------------------------------------------------------------
// Layer 0 (v==1): streams C row-by-row (1-row lookahead), exp -> half tile,
// writes E for covered rows (compacted by KC), same 4-row episodes.
// ---------------------------------------------------------------------------
__global__ __launch_bounds__(NTH, 4) void sink_l0(
    const float* __restrict__ C, half_t* __restrict__ E,
    const float* __restrict__ alpha, const float* __restrict__ d_eps,
    float* __restrict__ u, float* __restrict__ partial, int KC)
{
    const int t = threadIdx.x;
    const int rc = blockIdx.x;
    const int row0 = rc * RPB;
    const float inv_eps = 1.0f / d_eps[0];
    __shared__ float4_t sred[2][8];

    float acc[16];
#pragma unroll
    for (int j = 0; j < 16; ++j) acc[j] = 0.0f;

    const float4_t* Cb = (const float4_t*)C;
    half8_t* Eh = (half8_t*)E;

    float4_t cA[4], cB[4];
    auto loadRow = [&](float4_t (&d)[4], int lr) {
        const size_t ro = (size_t)(row0 + lr) * (NB / 4);
        d[0] = Cb[ro + 2 * t];
        d[1] = Cb[ro + 2 * t + 1];
        d[2] = Cb[ro + 1024 + 2 * t];
        d[3] = Cb[ro + 1024 + 2 * t + 1];
    };

    half8_t h[4][2];     // current batch tile
    float rs[4];

    auto procRow = [&](const float4_t (&c)[4], int b, int r, int lr) {
        half8_t h0, h1;
        float s = 0.0f;
        {
            const float e0 = __expf(-c[0].x * inv_eps);
            const float e1 = __expf(-c[0].y * inv_eps);
            const float e2 = __expf(-c[0].z * inv_eps);
            const float e3 = __expf(-c[0].w * inv_eps);
            const float e4 = __expf(-c[1].x * inv_eps);
            const float e5 = __expf(-c[1].y * inv_eps);
            const float e6 = __expf(-c[1].z * inv_eps);
            const float e7 = __expf(-c[1].w * inv_eps);
            h0[0] = (_Float16)e0; h0[1] = (_Float16)e1; h0[2] = (_Float16)e2;
            h0[3] = (_Float16)e3; h0[4] = (_Float16)e4; h0[5] = (_Float16)e5;
            h0[6] = (_Float16)e6; h0[7] = (_Float16)e7;
            s += ((e0 + e1) + (e2 + e3)) + ((e4 + e5) + (e6 + e7));
        }
        {
            const float e0 = __expf(-c[2].x * inv_eps);
            const float e1 = __expf(-c[2].y * inv_eps);
            const float e2 = __expf(-c[2].z * inv_eps);
            const float e3 = __expf(-c[2].w * inv_eps);
            const float e4 = __expf(-c[3].x * inv_eps);
            const float e5 = __expf(-c[3].y * inv_eps);
            const float e6 = __expf(-c[3].z * inv_eps);
            const float e7 = __expf(-c[3].w * inv_eps);
            h1[0] = (_Float16)e0; h1[1] = (_Float16)e1; h1[2] = (_Float16)e2;
            h1[3] = (_Float16)e3; h1[4] = (_Float16)e4; h1[5] = (_Float16)e5;
            h1[6] = (_Float16)e6; h1[7] = (_Float16)e7;
            s += ((e0 + e1) + (e2 + e3)) + ((e4 + e5) + (e6 + e7));
        }
        h[r][0] = h0;
        h[r][1] = h1;
        rs[r] = s;
        if (lr < KC) {
            const size_t eo = (size_t)(rc * KC + lr) * (NB / 8);
            Eh[eo + t] = h0;
            Eh[eo + 512 + t] = h1;
        }
    };

    auto episode = [&](int b, int par) {
        float rs0 = rs[0], rs1 = rs[1], rs2 = rs[2], rs3 = rs[3];
#pragma unroll
        for (int m = 1; m < 64; m <<= 1) {
            rs0 += __shfl_xor(rs0, m);
            rs1 += __shfl_xor(rs1, m);
            rs2 += __shfl_xor(rs2, m);
            rs3 += __shfl_xor(rs3, m);
        }
        if ((t & 63) == 0) sred[par][t >> 6] = float4_t{rs0, rs1, rs2, rs3};
        barrier_lds();
        float4_t S = sred[par][0];
#pragma unroll
        for (int w2 = 1; w2 < 8; ++w2) S += sred[par][w2];
        const int r0 = row0 + b * 4;
        const float u0 = alpha[r0] / S.x;
        const float u1 = alpha[r0 + 1] / S.y;
        const float u2 = alpha[r0 + 2] / S.z;
        const float u3 = alpha[r0 + 3] / S.w;
        if (t == 0) *(float4_t*)(u + r0) = float4_t{u0, u1, u2, u3};
#pragma unroll
        for (int j = 0; j < 8; ++j) {
            acc[j]     += u0 * (float)h[0][0][j] + u1 * (float)h[1][0][j] +
                          u2 * (float)h[2][0][j] + u3 * (float)h[3][0][j];
            acc[8 + j] += u0 * (float)h[0][1][j] + u1 * (float)h[1][1][j] +
                          u2 * (float)h[2][1][j] + u3 * (float)h[3][1][j];
        }
    };

    loadRow(cA, 0);
#pragma unroll
    for (int b = 0; b < 4; ++b) {
#pragma unroll
        for (int r = 0; r < 4; ++r) {
            const int lr = b * 4 + r;
            if (lr & 1) {
                if (lr < RPB - 1) loadRow(cA, lr + 1);
                procRow(cB, b, r, lr);
            } else {
                if (lr < RPB - 1) loadRow(cB, lr + 1);
                procRow(cA, b, r, lr);
            }
        }
        episode(b, b & 1);
    }

    float* pr = partial + (size_t)rc * NB;
    *(float4_t*)(pr + 8 * t)        = float4_t{acc[0], acc[1], acc[2], acc[3]};
    *(float4_t*)(pr + 8 * t + 4)    = float4_t{acc[4], acc[5], acc[6], acc[7]};
    *(float4_t*)(pr + 4096 + 8 * t)     = float4_t{acc[8], acc[9], acc[10], acc[11]};
    *(float4_t*)(pr + 4096 + 8 * t + 4) = float4_t{acc[12], acc[13], acc[14], acc[15]};
}

// ---------------------------------------------------------------------------
// Fallback steady path for KC<16 (tight workspace): covered rows from
// compacted E, the rest recomputed from C. Correctness-first.
// ---------------------------------------------------------------------------
__global__ __launch_bounds__(NTH, 4) void sink_fe_part(
    const half_t* __restrict__ E, const float* __restrict__ C,
    const float* __restrict__ v, const float* __restrict__ alpha,
    const float* __restrict__ d_eps, float* __restrict__ u,
    float* __restrict__ partial, int KC)
{
    const int t = threadIdx.x;
    const int rc = blockIdx.x;
    const int row0 = rc * RPB;
    const float inv_eps = 1.0f / d_eps[0];
    __shared__ float4_t sred[2][8];

    const float4_t* vv = (const float4_t*)v;
    const float4_t wA0 = vv[2 * t], wA1 = vv[2 * t + 1];
    const float4_t wB0 = vv[1024 + 2 * t], wB1 = vv[1024 + 2 * t + 1];

    float acc[16];
#pragma unroll
    for (int j = 0; j < 16; ++j) acc[j] = 0.0f;

    const half8_t* Eb = (const half8_t*)E;
    const float4_t* Cb = (const float4_t*)C;
    half8_t h[4][2];
    float rs[4];

    for (int b = 0; b < 4; ++b) {
#pragma unroll
        for (int r = 0; r < 4; ++r) {
            const int lr = b * 4 + r;
            half8_t h0, h1;
            if (lr < KC) {
                const size_t eo = (size_t)(rc * KC + lr) * (NB / 8);
                h0 = Eb[eo + t];
                h1 = Eb[eo + 512 + t];
            } else {
                const size_t ro = (size_t)(row0 + lr) * (NB / 4);
                const float4_t c0 = Cb[ro + 2 * t], c1 = Cb[ro + 2 * t + 1];
                const float4_t c2 = Cb[ro + 1024 + 2 * t], c3 = Cb[ro + 1024 + 2 * t + 1];
                h0[0] = (_Float16)__expf(-c0.x * inv_eps);
                h0[1] = (_Float16)__expf(-c0.y * inv_eps);
                h0[2] = (_Float16)__expf(-c0.z * inv_eps);
                h0[3] = (_Float16)__expf(-c0.w * inv_eps);
                h0[4] = (_Float16)__expf(-c1.x * inv_eps);
                h0[5] = (_Float16)__expf(-c1.y * inv_eps);
                h0[6] = (_Float16)__expf(-c1.z * inv_eps);
                h0[7] = (_Float16)__expf(-c1.w * inv_eps);
                h1[0] = (_Float16)__expf(-c2.x * inv_eps);
                h1[1] = (_Float16)__expf(-c2.y * inv_eps);
                h1[2] = (_Float16)__expf(-c2.z * inv_eps);
                h1[3] = (_Float16)__expf(-c2.w * inv_eps);
                h1[4] = (_Float16)__expf(-c3.x * inv_eps);
                h1[5] = (_Float16)__expf(-c3.y * inv_eps);
                h1[6] = (_Float16)__expf(-c3.z * inv_eps);
                h1[7] = (_Float16)__expf(-c3.w * inv_eps);
            }
            h[r][0] = h0;
            h[r][1] = h1;
            float x = 0.0f;
            x += (float)h0[0] * wA0.x + (float)h0[1] * wA0.y +
                 (float)h0[2] * wA0.z + (float)h0[3] * wA0.w;
            x += (float)h0[4] * wA1.x + (float)h0[5] * wA1.y +
                 (float)h0[6] * wA1.z + (float)h0[7] * wA1.w;
            x += (float)h1[0] * wB0.x + (float)h1[1] * wB0.y +
                 (float)h1[2] * wB0.z + (float)h1[3] * wB0.w;
            x += (float)h1[4] * wB1.x + (float)h1[5] * wB1.y +
                 (float)h1[6] * wB1.z + (float)h1[7] * wB1.w;
            rs[r] = x;
        }
        float rs0 = rs[0], rs1 = rs[1], rs2 = rs[2], rs3 = rs[3];
#pragma unroll
        for (int m = 1; m < 64; m <<= 1) {
            rs0 += __shfl_xor(rs0, m);
            rs1 += __shfl_xor(rs1, m);
            rs2 += __shfl_xor(rs2, m);
            rs3 += __shfl_xor(rs3, m);
        }
        const int par = b & 1;
        if ((t & 63) == 0) sred[par][t >> 6] = float4_t{rs0, rs1, rs2, rs3};
        barrier_lds();
        float4_t S = sred[par][0];
#pragma unroll
        for (int w2 = 1; w2 < 8; ++w2) S += sred[par][w2];
        const int r0 = row0 + b * 4;
        const float u0 = alpha[r0] / S.x;
        const float u1 = alpha[r0 + 1] / S.y;
        const float u2 = alpha[r0 + 2] / S.z;
        const float u3 = alpha[r0 + 3] / S.w;
        if (t == 0) *(float4_t*)(u + r0) = float4_t{u0, u1, u2, u3};
#pragma unroll
        for (int j = 0; j < 8; ++j) {
            acc[j]     += u0 * (float)h[0][0][j] + u1 * (float)h[1][0][j] +
                          u2 * (float)h[2][0][j] + u3 * (float)h[3][0][j];
            acc[8 + j] += u0 * (float)h[0][1][j] + u1 * (float)h[1][1][j] +
                          u2 * (float)h[2][1][j] + u3 * (float)h[3][1][j];
        }
    }

    float* pr = partial + (size_t)rc * NB;
    *(float4_t*)(pr + 8 * t)        = float4_t{acc[0], acc[1], acc[2], acc[3]};
    *(float4_t*)(pr + 8 * t + 4)    = float4_t{acc[4], acc[5], acc[6], acc[7]};
    *(float4_t*)(pr + 4096 + 8 * t)     = float4_t{acc[8], acc[9], acc[10], acc[11]};
    *(float4_t*)(pr + 4096 + 8 * t + 4) = float4_t{acc[12], acc[13], acc[14], acc[15]};
}

// ---------------------------------------------------------------------------
// v[j] = beta[j] / sum_rc partial[rc][j].  256 blocks x (32 cols x 8 slices).
// ---------------------------------------------------------------------------
__global__ __launch_bounds__(256) void sink_v_combine(
    const float* __restrict__ partial, const float* __restrict__ beta,
    float* __restrict__ v)
{
    const int c = blockIdx.x * 32 + (threadIdx.x & 31);
    const int sl = threadIdx.x >> 5;
    float s = 0.0f;
#pragma unroll 4
    for (int i = sl; i < NBLK; i += 8) s += partial[(size_t)i * NB + c];
    __shared__ float sm[8][32];
    sm[sl][threadIdx.x & 31] = s;
    __syncthreads();
    if (threadIdx.x < 32) {
        float tot = 0.0f;
#pragma unroll
        for (int k = 0; k < 8; ++k) tot += sm[k][threadIdx.x];
        v[c] = beta[c] / tot;
    }
}

// ---------------------------------------------------------------------------
// f = eps*log(u), g = eps*log(v), concatenated into d_out.
// ---------------------------------------------------------------------------
__global__ __launch_bounds__(256) void sink_finalize(
    const float* __restrict__ u, const float* __restrict__ v,
    const float* __restrict__ d_eps, float* __restrict__ out)
{
    const int i = blockIdx.x * 256 + threadIdx.x;
    const float eps = d_eps[0];
    if (i < NA) {
        out[i] = eps * logf(u[i]);
    } else if (i < NA + NB) {
        out[i] = eps * logf(v[i - NA]);
    }
}

extern "C" void kernel_launch(void* const* d_in, const int* in_sizes, int n_in,
                              void* d_out, int out_size, void* d_ws, size_t ws_size,
                              hipStream_t stream)
{
    const float* alpha = (const float*)d_in[0];
    const float* beta  = (const float*)d_in[1];
    const float* C     = (const float*)d_in[2];
    const float* d_eps = (const float*)d_in[3];
    float* out = (float*)d_out;

    const size_t pB   = (size_t)NBLK * NB * sizeof(float);   // 16.78 MB
    const size_t vecB = (size_t)NA * sizeof(float);          // 32 KiB
    const size_t perK = (size_t)NBLK * NB * sizeof(half_t);  // 8.39 MB per covered row/chunk
    const size_t eFull = perK * RPB;                         // 134.2 MB

    int KC = RPB;
    {
        size_t avail = (ws_size > pB + 2 * vecB) ? ws_size - pB - 2 * vecB : 0;
        if (avail < eFull) {
            KC = (int)(avail / perK);
            if (KC > RPB) KC = RPB;
            KC &= ~1;
        }
    }

    char* ws = (char*)d_ws;
    size_t off = 0;
    half_t* E = (half_t*)ws; off += perK * KC;
    float* partial = (float*)(ws + off); off += pB;
    float* u = (float*)(ws + off); off += vecB;
    float* v = (float*)(ws + off);

    const dim3 blkF(NTH), blkS(256);
    const dim3 gridF(NBLK);
    const dim3 gridC(NB / 32);
    const dim3 gridFin((NA + NB) / 256);

    for (int layer = 0; layer < N_LAYERS; ++layer) {
        if (layer == 0) {
            sink_l0<<<gridF, blkF, 0, stream>>>(C, E, alpha, d_eps, u, partial, KC);
        } else if (KC == RPB) {
            sink_fe_full<<<gridF, blkF, 0, stream>>>(E, v, alpha, u, partial);
        } else {
            sink_fe_part<<<gridF, blkF, 0, stream>>>(E, C, v, alpha, d_eps, u,
                                                     partial, KC);
        }
        sink_v_combine<<<gridC, blkS, 0, stream>>>(partial, beta, v);
    }
    sink_finalize<<<gridFin, blkS, 0, stream>>>(u, v, d_eps, out);
}

// Round 4
// 1359.275 us; speedup vs baseline: 1.7680x; 1.7680x over previous
//
#include <hip/hip_runtime.h>

#define NA 8192
#define NB 8192
#define N_LAYERS 16
#define RPB 16          // rows per fused block
#define NBLK 512        // fused grid = NA/RPB
#define NTH 512         // threads per fused block; thread owns cols {8t..8t+7} u {4096+8t..+7}

typedef _Float16 half_t;
typedef _Float16 half8_t __attribute__((ext_vector_type(8)));
typedef float float4_t __attribute__((ext_vector_type(4)));

// LDS-only barrier: does NOT drain vmcnt, so global prefetch loads for the
// next batch stay in flight across the reduction episode.
__device__ __forceinline__ void barrier_lds() {
    asm volatile("s_waitcnt lgkmcnt(0)" ::: "memory");
    __builtin_amdgcn_s_barrier();
    asm volatile("" ::: "memory");
}

// NOTE on __launch_bounds__: measured on this toolchain (rounds 2/3),
// the 2nd arg behaves as min BLOCKS/CU (CUDA semantics): (512,2) -> 128
// VGPR cap, (512,4) -> 64 VGPR cap (caused massive spills). All fused
// kernels need ~112 VGPRs -> use (NTH, 2).

// ---------------------------------------------------------------------------
// Steady layers, full-E path (KC==16). Block = 16 rows, 4 batches of 4 rows.
// Per batch: dots vs register-resident v-slice -> ONE butterfly+barrier
// episode for 4 rows -> u -> column accumulation from the register tile.
// E is read from global exactly once per layer.
// ---------------------------------------------------------------------------
__global__ __launch_bounds__(NTH, 2) void sink_fe_full(
    const half_t* __restrict__ E, const float* __restrict__ v,
    const float* __restrict__ alpha, float* __restrict__ u,
    float* __restrict__ partial)
{
    const int t = threadIdx.x;
    const int rc = blockIdx.x;
    const int row0 = rc * RPB;
    __shared__ float4_t sred[2][8];          // [parity][wave] : 4 row-sums

    // v weights for owned cols (loaded once)
    const float4_t* vv = (const float4_t*)v;
    const float4_t wA0 = vv[2 * t], wA1 = vv[2 * t + 1];
    const float4_t wB0 = vv[1024 + 2 * t], wB1 = vv[1024 + 2 * t + 1];

    float acc[16];
#pragma unroll
    for (int j = 0; j < 16; ++j) acc[j] = 0.0f;

    const half8_t* Eb = (const half8_t*)E;
    const size_t rbase = (size_t)row0 * (NB / 8);

    half8_t eC[4][2], eN[4][2];
    auto loadB = [&](half8_t (&d)[4][2], int b) {
#pragma unroll
        for (int r = 0; r < 4; ++r) {
            const size_t ro = rbase + (size_t)(b * 4 + r) * (NB / 8);
            d[r][0] = Eb[ro + t];
            d[r][1] = Eb[ro + 512 + t];
        }
    };

    auto episode = [&](const half8_t (&e)[4][2], int b, int par) {
        float rs0, rs1, rs2, rs3;
        {
            float s[4];
#pragma unroll
            for (int r = 0; r < 4; ++r) {
                float x = 0.0f;
                x += (float)e[r][0][0] * wA0.x + (float)e[r][0][1] * wA0.y +
                     (float)e[r][0][2] * wA0.z + (float)e[r][0][3] * wA0.w;
                x += (float)e[r][0][4] * wA1.x + (float)e[r][0][5] * wA1.y +
                     (float)e[r][0][6] * wA1.z + (float)e[r][0][7] * wA1.w;
                x += (float)e[r][1][0] * wB0.x + (float)e[r][1][1] * wB0.y +
                     (float)e[r][1][2] * wB0.z + (float)e[r][1][3] * wB0.w;
                x += (float)e[r][1][4] * wB1.x + (float)e[r][1][5] * wB1.y +
                     (float)e[r][1][6] * wB1.z + (float)e[r][1][7] * wB1.w;
                s[r] = x;
            }
            rs0 = s[0]; rs1 = s[1]; rs2 = s[2]; rs3 = s[3];
        }
#pragma unroll
        for (int m = 1; m < 64; m <<= 1) {   // 4 independent 6-deep chains
            rs0 += __shfl_xor(rs0, m);
            rs1 += __shfl_xor(rs1, m);
            rs2 += __shfl_xor(rs2, m);
            rs3 += __shfl_xor(rs3, m);
        }
        if ((t & 63) == 0) sred[par][t >> 6] = float4_t{rs0, rs1, rs2, rs3};
        barrier_lds();
        float4_t S = sred[par][0];
#pragma unroll
        for (int w2 = 1; w2 < 8; ++w2) S += sred[par][w2];

        const int r0 = row0 + b * 4;
        const float u0 = alpha[r0] / S.x;
        const float u1 = alpha[r0 + 1] / S.y;
        const float u2 = alpha[r0 + 2] / S.z;
        const float u3 = alpha[r0 + 3] / S.w;
        if (t == 0) *(float4_t*)(u + r0) = float4_t{u0, u1, u2, u3};

#pragma unroll
        for (int j = 0; j < 8; ++j) {
            acc[j]     += u0 * (float)e[0][0][j] + u1 * (float)e[1][0][j] +
                          u2 * (float)e[2][0][j] + u3 * (float)e[3][0][j];
            acc[8 + j] += u0 * (float)e[0][1][j] + u1 * (float)e[1][1][j] +
                          u2 * (float)e[2][1][j] + u3 * (float)e[3][1][j];
        }
    };

    loadB(eC, 0);
    loadB(eN, 1);          // 2 batches in flight
    episode(eC, 0, 0);
    loadB(eC, 2);
    episode(eN, 1, 1);
    loadB(eN, 3);
    episode(eC, 2, 0);
    episode(eN, 3, 1);

    // partial[rc][owned cols]
    float* pr = partial + (size_t)rc * NB;
    *(float4_t*)(pr + 8 * t)        = float4_t{acc[0], acc[1], acc[2], acc[3]};
    *(float4_t*)(pr + 8 * t + 4)    = float4_t{acc[4], acc[5], acc[6], acc[7]};
    *(float4_t*)(pr + 4096 + 8 * t)     = float4_t{acc[8], acc[9], acc[10], acc[11]};
    *(float4_t*)(pr + 4096 + 8 * t + 4) = float4_t{acc[12], acc[13], acc[14], acc[15]};
}

// ---------------------------------------------------------------------------
// Layer 0 (v==1): streams C row-by-row (1-row lookahead), exp -> half tile,
// writes E for covered rows (compacted by KC), same 4-row episodes.
// ---------------------------------------------------------------------------
__global__ __launch_bounds__(NTH, 2) void sink_l0(
    const float* __restrict__ C, half_t* __restrict__ E,
    const float* __restrict__ alpha, const float* __restrict__ d_eps,
    float* __restrict__ u, float* __restrict__ partial, int KC)
{
    const int t = threadIdx.x;
    const int rc = blockIdx.x;
    const int row0 = rc * RPB;
    const float inv_eps = 1.0f / d_eps[0];
    __shared__ float4_t sred[2][8];

    float acc[16];
#pragma unroll
    for (int j = 0; j < 16; ++j) acc[j] = 0.0f;

    const float4_t* Cb = (const float4_t*)C;
    half8_t* Eh = (half8_t*)E;

    float4_t cA[4], cB[4];
    auto loadRow = [&](float4_t (&d)[4], int lr) {
        const size_t ro = (size_t)(row0 + lr) * (NB / 4);
        d[0] = Cb[ro + 2 * t];
        d[1] = Cb[ro + 2 * t + 1];
        d[2] = Cb[ro + 1024 + 2 * t];
        d[3] = Cb[ro + 1024 + 2 * t + 1];
    };

    half8_t h[4][2];     // current batch tile
    float rs[4];

    auto procRow = [&](const float4_t (&c)[4], int b, int r, int lr) {
        half8_t h0, h1;
        float s = 0.0f;
        {
            const float e0 = __expf(-c[0].x * inv_eps);
            const float e1 = __expf(-c[0].y * inv_eps);
            const float e2 = __expf(-c[0].z * inv_eps);
            const float e3 = __expf(-c[0].w * inv_eps);
            const float e4 = __expf(-c[1].x * inv_eps);
            const float e5 = __expf(-c[1].y * inv_eps);
            const float e6 = __expf(-c[1].z * inv_eps);
            const float e7 = __expf(-c[1].w * inv_eps);
            h0[0] = (_Float16)e0; h0[1] = (_Float16)e1; h0[2] = (_Float16)e2;
            h0[3] = (_Float16)e3; h0[4] = (_Float16)e4; h0[5] = (_Float16)e5;
            h0[6] = (_Float16)e6; h0[7] = (_Float16)e7;
            s += ((e0 + e1) + (e2 + e3)) + ((e4 + e5) + (e6 + e7));
        }
        {
            const float e0 = __expf(-c[2].x * inv_eps);
            const float e1 = __expf(-c[2].y * inv_eps);
            const float e2 = __expf(-c[2].z * inv_eps);
            const float e3 = __expf(-c[2].w * inv_eps);
            const float e4 = __expf(-c[3].x * inv_eps);
            const float e5 = __expf(-c[3].y * inv_eps);
            const float e6 = __expf(-c[3].z * inv_eps);
            const float e7 = __expf(-c[3].w * inv_eps);
            h1[0] = (_Float16)e0; h1[1] = (_Float16)e1; h1[2] = (_Float16)e2;
            h1[3] = (_Float16)e3; h1[4] = (_Float16)e4; h1[5] = (_Float16)e5;
            h1[6] = (_Float16)e6; h1[7] = (_Float16)e7;
            s += ((e0 + e1) + (e2 + e3)) + ((e4 + e5) + (e6 + e7));
        }
        h[r][0] = h0;
        h[r][1] = h1;
        rs[r] = s;
        if (lr < KC) {
            const size_t eo = (size_t)(rc * KC + lr) * (NB / 8);
            Eh[eo + t] = h0;
            Eh[eo + 512 + t] = h1;
        }
    };

    auto episode = [&](int b, int par) {
        float rs0 = rs[0], rs1 = rs[1], rs2 = rs[2], rs3 = rs[3];
#pragma unroll
        for (int m = 1; m < 64; m <<= 1) {
            rs0 += __shfl_xor(rs0, m);
            rs1 += __shfl_xor(rs1, m);
            rs2 += __shfl_xor(rs2, m);
            rs3 += __shfl_xor(rs3, m);
        }
        if ((t & 63) == 0) sred[par][t >> 6] = float4_t{rs0, rs1, rs2, rs3};
        barrier_lds();
        float4_t S = sred[par][0];
#pragma unroll
        for (int w2 = 1; w2 < 8; ++w2) S += sred[par][w2];
        const int r0 = row0 + b * 4;
        const float u0 = alpha[r0] / S.x;
        const float u1 = alpha[r0 + 1] / S.y;
        const float u2 = alpha[r0 + 2] / S.z;
        const float u3 = alpha[r0 + 3] / S.w;
        if (t == 0) *(float4_t*)(u + r0) = float4_t{u0, u1, u2, u3};
#pragma unroll
        for (int j = 0; j < 8; ++j) {
            acc[j]     += u0 * (float)h[0][0][j] + u1 * (float)h[1][0][j] +
                          u2 * (float)h[2][0][j] + u3 * (float)h[3][0][j];
            acc[8 + j] += u0 * (float)h[0][1][j] + u1 * (float)h[1][1][j] +
                          u2 * (float)h[2][1][j] + u3 * (float)h[3][1][j];
        }
    };

    loadRow(cA, 0);
#pragma unroll
    for (int b = 0; b < 4; ++b) {
#pragma unroll
        for (int r = 0; r < 4; ++r) {
            const int lr = b * 4 + r;
            if (lr & 1) {
                if (lr < RPB - 1) loadRow(cA, lr + 1);
                procRow(cB, b, r, lr);
            } else {
                if (lr < RPB - 1) loadRow(cB, lr + 1);
                procRow(cA, b, r, lr);
            }
        }
        episode(b, b & 1);
    }

    float* pr = partial + (size_t)rc * NB;
    *(float4_t*)(pr + 8 * t)        = float4_t{acc[0], acc[1], acc[2], acc[3]};
    *(float4_t*)(pr + 8 * t + 4)    = float4_t{acc[4], acc[5], acc[6], acc[7]};
    *(float4_t*)(pr + 4096 + 8 * t)     = float4_t{acc[8], acc[9], acc[10], acc[11]};
    *(float4_t*)(pr + 4096 + 8 * t + 4) = float4_t{acc[12], acc[13], acc[14], acc[15]};
}

// ---------------------------------------------------------------------------
// Fallback steady path for KC<16 (tight workspace): covered rows from
// compacted E, the rest recomputed from C. Correctness-first.
// ---------------------------------------------------------------------------
__global__ __launch_bounds__(NTH, 2) void sink_fe_part(
    const half_t* __restrict__ E, const float* __restrict__ C,
    const float* __restrict__ v, const float* __restrict__ alpha,
    const float* __restrict__ d_eps, float* __restrict__ u,
    float* __restrict__ partial, int KC)
{
    const int t = threadIdx.x;
    const int rc = blockIdx.x;
    const int row0 = rc * RPB;
    const float inv_eps = 1.0f / d_eps[0];
    __shared__ float4_t sred[2][8];

    const float4_t* vv = (const float4_t*)v;
    const float4_t wA0 = vv[2 * t], wA1 = vv[2 * t + 1];
    const float4_t wB0 = vv[1024 + 2 * t], wB1 = vv[1024 + 2 * t + 1];

    float acc[16];
#pragma unroll
    for (int j = 0; j < 16; ++j) acc[j] = 0.0f;

    const half8_t* Eb = (const half8_t*)E;
    const float4_t* Cb = (const float4_t*)C;
    half8_t h[4][2];
    float rs[4];

    for (int b = 0; b < 4; ++b) {
#pragma unroll
        for (int r = 0; r < 4; ++r) {
            const int lr = b * 4 + r;
            half8_t h0, h1;
            if (lr < KC) {
                const size_t eo = (size_t)(rc * KC + lr) * (NB / 8);
                h0 = Eb[eo + t];
                h1 = Eb[eo + 512 + t];
            } else {
                const size_t ro = (size_t)(row0 + lr) * (NB / 4);
                const float4_t c0 = Cb[ro + 2 * t], c1 = Cb[ro + 2 * t + 1];
                const float4_t c2 = Cb[ro + 1024 + 2 * t], c3 = Cb[ro + 1024 + 2 * t + 1];
                h0[0] = (_Float16)__expf(-c0.x * inv_eps);
                h0[1] = (_Float16)__expf(-c0.y * inv_eps);
                h0[2] = (_Float16)__expf(-c0.z * inv_eps);
                h0[3] = (_Float16)__expf(-c0.w * inv_eps);
                h0[4] = (_Float16)__expf(-c1.x * inv_eps);
                h0[5] = (_Float16)__expf(-c1.y * inv_eps);
                h0[6] = (_Float16)__expf(-c1.z * inv_eps);
                h0[7] = (_Float16)__expf(-c1.w * inv_eps);
                h1[0] = (_Float16)__expf(-c2.x * inv_eps);
                h1[1] = (_Float16)__expf(-c2.y * inv_eps);
                h1[2] = (_Float16)__expf(-c2.z * inv_eps);
                h1[3] = (_Float16)__expf(-c2.w * inv_eps);
                h1[4] = (_Float16)__expf(-c3.x * inv_eps);
                h1[5] = (_Float16)__expf(-c3.y * inv_eps);
                h1[6] = (_Float16)__expf(-c3.z * inv_eps);
                h1[7] = (_Float16)__expf(-c3.w * inv_eps);
            }
            h[r][0] = h0;
            h[r][1] = h1;
            float x = 0.0f;
            x += (float)h0[0] * wA0.x + (float)h0[1] * wA0.y +
                 (float)h0[2] * wA0.z + (float)h0[3] * wA0.w;
            x += (float)h0[4] * wA1.x + (float)h0[5] * wA1.y +
                 (float)h0[6] * wA1.z + (float)h0[7] * wA1.w;
            x += (float)h1[0] * wB0.x + (float)h1[1] * wB0.y +
                 (float)h1[2] * wB0.z + (float)h1[3] * wB0.w;
            x += (float)h1[4] * wB1.x + (float)h1[5] * wB1.y +
                 (float)h1[6] * wB1.z + (float)h1[7] * wB1.w;
            rs[r] = x;
        }
        float rs0 = rs[0], rs1 = rs[1], rs2 = rs[2], rs3 = rs[3];
#pragma unroll
        for (int m = 1; m < 64; m <<= 1) {
            rs0 += __shfl_xor(rs0, m);
            rs1 += __shfl_xor(rs1, m);
            rs2 += __shfl_xor(rs2, m);
            rs3 += __shfl_xor(rs3, m);
        }
        const int par = b & 1;
        if ((t & 63) == 0) sred[par][t >> 6] = float4_t{rs0, rs1, rs2, rs3};
        barrier_lds();
        float4_t S = sred[par][0];
#pragma unroll
        for (int w2 = 1; w2 < 8; ++w2) S += sred[par][w2];
        const int r0 = row0 + b * 4;
        const float u0 = alpha[r0] / S.x;
        const float u1 = alpha[r0 + 1] / S.y;
        const float u2 = alpha[r0 + 2] / S.z;
        const float u3 = alpha[r0 + 3] / S.w;
        if (t == 0) *(float4_t*)(u + r0) = float4_t{u0, u1, u2, u3};
#pragma unroll
        for (int j = 0; j < 8; ++j) {
            acc[j]     += u0 * (float)h[0][0][j] + u1 * (float)h[1][0][j] +
                          u2 * (float)h[2][0][j] + u3 * (float)h[3][0][j];
            acc[8 + j] += u0 * (float)h[0][1][j] + u1 * (float)h[1][1][j] +
                          u2 * (float)h[2][1][j] + u3 * (float)h[3][1][j];
        }
    }

    float* pr = partial + (size_t)rc * NB;
    *(float4_t*)(pr + 8 * t)        = float4_t{acc[0], acc[1], acc[2], acc[3]};
    *(float4_t*)(pr + 8 * t + 4)    = float4_t{acc[4], acc[5], acc[6], acc[7]};
    *(float4_t*)(pr + 4096 + 8 * t)     = float4_t{acc[8], acc[9], acc[10], acc[11]};
    *(float4_t*)(pr + 4096 + 8 * t + 4) = float4_t{acc[12], acc[13], acc[14], acc[15]};
}

// ---------------------------------------------------------------------------
// v[j] = beta[j] / sum_rc partial[rc][j].  256 blocks x (32 cols x 8 slices).
// ---------------------------------------------------------------------------
__global__ __launch_bounds__(256) void sink_v_combine(
    const float* __restrict__ partial, const float* __restrict__ beta,
    float* __restrict__ v)
{
    const int c = blockIdx.x * 32 + (threadIdx.x & 31);
    const int sl = threadIdx.x >> 5;
    float s = 0.0f;
#pragma unroll 4
    for (int i = sl; i < NBLK; i += 8) s += partial[(size_t)i * NB + c];
    __shared__ float sm[8][32];
    sm[sl][threadIdx.x & 31] = s;
    __syncthreads();
    if (threadIdx.x < 32) {
        float tot = 0.0f;
#pragma unroll
        for (int k = 0; k < 8; ++k) tot += sm[k][threadIdx.x];
        v[c] = beta[c] / tot;
    }
}

// ---------------------------------------------------------------------------
// f = eps*log(u), g = eps*log(v), concatenated into d_out.
// ---------------------------------------------------------------------------
__global__ __launch_bounds__(256) void sink_finalize(
    const float* __restrict__ u, const float* __restrict__ v,
    const float* __restrict__ d_eps, float* __restrict__ out)
{
    const int i = blockIdx.x * 256 + threadIdx.x;
    const float eps = d_eps[0];
    if (i < NA) {
        out[i] = eps * logf(u[i]);
    } else if (i < NA + NB) {
        out[i] = eps * logf(v[i - NA]);
    }
}

extern "C" void kernel_launch(void* const* d_in, const int* in_sizes, int n_in,
                              void* d_out, int out_size, void* d_ws, size_t ws_size,
                              hipStream_t stream)
{
    const float* alpha = (const float*)d_in[0];
    const float* beta  = (const float*)d_in[1];
    const float* C     = (const float*)d_in[2];
    const float* d_eps = (const float*)d_in[3];
    float* out = (float*)d_out;

    const size_t pB   = (size_t)NBLK * NB * sizeof(float);   // 16.78 MB
    const size_t vecB = (size_t)NA * sizeof(float);          // 32 KiB
    const size_t perK = (size_t)NBLK * NB * sizeof(half_t);  // 8.39 MB per covered row/chunk
    const size_t eFull = perK * RPB;                         // 134.2 MB

    int KC = RPB;
    {
        size_t avail = (ws_size > pB + 2 * vecB) ? ws_size - pB - 2 * vecB : 0;
        if (avail < eFull) {
            KC = (int)(avail / perK);
            if (KC > RPB) KC = RPB;
            KC &= ~1;
        }
    }

    char* ws = (char*)d_ws;
    size_t off = 0;
    half_t* E = (half_t*)ws; off += perK * KC;
    float* partial = (float*)(ws + off); off += pB;
    float* u = (float*)(ws + off); off += vecB;
    float* v = (float*)(ws + off);

    const dim3 blkF(NTH), blkS(256);
    const dim3 gridF(NBLK);
    const dim3 gridC(NB / 32);
    const dim3 gridFin((NA + NB) / 256);

    for (int layer = 0; layer < N_LAYERS; ++layer) {
        if (layer == 0) {
            sink_l0<<<gridF, blkF, 0, stream>>>(C, E, alpha, d_eps, u, partial, KC);
        } else if (KC == RPB) {
            sink_fe_full<<<gridF, blkF, 0, stream>>>(E, v, alpha, u, partial);
        } else {
            sink_fe_part<<<gridF, blkF, 0, stream>>>(E, C, v, alpha, d_eps, u,
                                                     partial, KC);
        }
        sink_v_combine<<<gridC, blkS, 0, stream>>>(partial, beta, v);
    }
    sink_finalize<<<gridFin, blkS, 0, stream>>>(u, v, d_eps, out);
}